// Round 13
// baseline (615.974 us; speedup 1.0000x reference)
//
#include <hip/hip_runtime.h>
#include <hip/hip_fp16.h>

// Round 20: 3-dispatch pipeline — memset(1KB) + scatter + scan-with-fused-
//   reduce. R19 residual analysis: 374 - scan 182 - scatter ~111 = ~81us
//   for cursor_init + reduce + gaps -> ~15us per dispatch boundary.
//   Changes vs R19 (two small orthogonal edits):
//   (1) cursors become RELATIVE fills, zeroed by one hipMemsetAsync(1KB)
//       (also zeroes done[]); scatter computes abs base = b*cap + g_rel.
//   (2) last-slice-block reduce: each scan block writes its slab ->
//       __threadfence -> atomicAdd(done[c]); ticket NSLICES-1 fences and
//       reduces the chunk's 10 f16 slabs -> out (f32). No spin: safe
//       under any dispatch order/residency. chunk_reduce_h dispatch gone.
//   Scatter/scan cores otherwise byte-identical to R19 (373.8us PASS).
// Entry = (other_idx(18b) | dest_local(12b)<<18, w=0.5/d).

#define BLOCK 1024
#define NSLICES 10
#define CT_BLOCK 256
#define SC_BLOCK 256
#define SC_PPT 8
#define SC_NENT (SC_BLOCK * SC_PPT * 2)   // 4096 entries staged per block
#define CA_BITS 12        // chunk = 4096 atoms
#define NCHUNK 49
#define NSLOT (NCHUNK * 4)                // 196
#define PLANE_PAD 16      // half2s; plane1 bank offset +16
#define CAP_MIN 345024u   // 327,680 mean + ~30 sigma, 64-aligned
#define FB_NSL 10
#define FB_UNROLL 8

__device__ __forceinline__ void fadd(float* p, float v) {
#if defined(__HIP_DEVICE_COMPILE__)
    unsafeAtomicAdd(p, v);
#else
    atomicAdd(p, v);
#endif
}

// Native packed-f16 LDS atomic add (no return), via inline asm.
// NOTE: invisible to compiler waitcnt tracking — every kernel using this
// MUST execute lds_drain() before a barrier whose consumers read the cells.
__device__ __forceinline__ void pkadd(__half2* p, float lo, float hi) {
#if defined(__HIP_DEVICE_COMPILE__)
    __half2 v = __float22half2_rn(make_float2(lo, hi));
    unsigned bits;
    __builtin_memcpy(&bits, &v, 4);
    unsigned off = (unsigned)(unsigned long long)(void*)p;
    asm volatile("ds_pk_add_f16 %0, %1" :: "v"(off), "v"(bits) : "memory");
#else
    (void)p; (void)lo; (void)hi;
#endif
}

__device__ __forceinline__ void lds_drain() {
#if defined(__HIP_DEVICE_COMPILE__)
    asm volatile("s_waitcnt lgkmcnt(0)" ::: "memory");
#endif
}

// ---------------- Pass 0 (fallback only): count via private LDS hists -----
__global__ __launch_bounds__(CT_BLOCK) void bucket_count(
    const int4* __restrict__ idx2, unsigned* __restrict__ counts, int npairs)
{
    __shared__ unsigned ph[CT_BLOCK * NCHUNK];   // 50.2 KB, thread-major
    unsigned* mine = ph + threadIdx.x * NCHUNK;
#pragma unroll
    for (int b = 0; b < NCHUNK; ++b) mine[b] = 0;
    __syncthreads();

    const int n4 = npairs >> 1;                  // int4 = 2 pairs
    const int stride = gridDim.x * CT_BLOCK;
    for (int q = blockIdx.x * CT_BLOCK + threadIdx.x; q < n4; q += stride) {
        int4 v = idx2[q];
        ++mine[(unsigned)v.x >> CA_BITS];
        ++mine[(unsigned)v.y >> CA_BITS];
        ++mine[(unsigned)v.z >> CA_BITS];
        ++mine[(unsigned)v.w >> CA_BITS];
    }
    if ((npairs & 1) && blockIdx.x == 0 && threadIdx.x == 0) {
        const int2* idx = (const int2*)idx2;
        int2 ij = idx[npairs - 1];
        ++mine[(unsigned)ij.x >> CA_BITS];
        ++mine[(unsigned)ij.y >> CA_BITS];
    }
    __syncthreads();

    for (int b = threadIdx.x; b < NCHUNK; b += CT_BLOCK) {
        unsigned s = 0;
#pragma unroll 8
        for (int t = 0; t < CT_BLOCK; ++t) s += ph[t * NCHUNK + b];
        if (s) atomicAdd(&counts[b], s);
    }
}

// ---------------- prefix sum (fallback only) ----------------
__global__ void bucket_prefix(const unsigned* __restrict__ counts,
                              unsigned* __restrict__ offsets,
                              unsigned* __restrict__ cursors, int nbuckets)
{
    if (threadIdx.x == 0 && blockIdx.x == 0) {
        unsigned acc = 0;
        for (int b = 0; b < nbuckets; ++b) {
            offsets[b] = acc; cursors[b] = acc; acc += counts[b];
        }
        offsets[nbuckets] = acc;
    }
}

// ---------------- Pass A: scatter, LDS-staged for coalesced writes --------
// FIX: cursors are RELATIVE fills (start 0); abs base = b*cap + g_rel.
template<bool FIX>
__global__ __launch_bounds__(SC_BLOCK) void bucket_scatter(
    const int2*  __restrict__ idx, const float* __restrict__ dist,
    uint2* __restrict__ entries, unsigned* __restrict__ cursors, int npairs,
    unsigned cap)
{
    __shared__ unsigned hist[NSLOT];          // per-slot counts
    __shared__ unsigned lbase[NSLOT];         // exclusive local prefix
    __shared__ unsigned rbase[NSLOT];         // global base per slot
    __shared__ unsigned scanbuf[SC_BLOCK];
    __shared__ uint2    stage[SC_NENT];       // 32 KB
    __shared__ unsigned char slotid[SC_NENT]; // 4 KB
    for (int b = threadIdx.x; b < NSLOT; b += SC_BLOCK) hist[b] = 0;
    __syncthreads();

    const int p0 = blockIdx.x * (SC_BLOCK * SC_PPT) + threadIdx.x;
    const unsigned r = threadIdx.x & 3;
    unsigned key[2 * SC_PPT];
    unsigned brk[2 * SC_PPT];       // slot(8b: b*4+r) | rank<<8
    float    wv[SC_PPT];

#pragma unroll
    for (int k = 0; k < SC_PPT; ++k) {
        int p = p0 + k * SC_BLOCK;
        if (p < npairs) {
            int2 ij = idx[p];
            wv[k] = 0.5f / dist[p];
            unsigned s0 = (((unsigned)ij.x >> CA_BITS) << 2) + r;
            unsigned s1 = (((unsigned)ij.y >> CA_BITS) << 2) + r;
            key[2 * k]     = (unsigned)ij.y | (((unsigned)ij.x & ((1u << CA_BITS) - 1)) << 18);
            brk[2 * k]     = s0 | (atomicAdd(&hist[s0], 1u) << 8);
            key[2 * k + 1] = (unsigned)ij.x | (((unsigned)ij.y & ((1u << CA_BITS) - 1)) << 18);
            brk[2 * k + 1] = s1 | (atomicAdd(&hist[s1], 1u) << 8);
        } else {
            brk[2 * k] = brk[2 * k + 1] = 0xFFFFFFFFu;
        }
    }
    __syncthreads();

    // exclusive prefix over 196 slot counts (block Hillis-Steele, 256 wide)
    {
        const int t = threadIdx.x;
        unsigned v = (t < NSLOT) ? hist[t] : 0u;
        scanbuf[t] = v;
        __syncthreads();
        for (int off = 1; off < SC_BLOCK; off <<= 1) {
            unsigned x = (t >= off) ? scanbuf[t - off] : 0u;
            __syncthreads();
            scanbuf[t] += x;
            __syncthreads();
        }
        if (t < NSLOT) lbase[t] = scanbuf[t] - v;   // exclusive prefix
    }
    // global reservation per bucket (replica-ordered)
    if (threadIdx.x < NCHUNK) {
        int b = threadIdx.x;
        unsigned h0 = hist[4 * b], h1 = hist[4 * b + 1], h2 = hist[4 * b + 2], h3 = hist[4 * b + 3];
        unsigned tot = h0 + h1 + h2 + h3;
        unsigned g;
        if (FIX) {
            unsigned grel = tot ? atomicAdd(&cursors[b], tot) : 0u;
            // memory-safety clamp; capb slack >= 30 sigma so never triggers
            if (tot && grel + tot > cap) grel = cap - tot;
            g = (unsigned)b * cap + grel;
        } else {
            g = tot ? atomicAdd(&cursors[b], tot) : 0u;
        }
        rbase[4 * b]     = g;
        rbase[4 * b + 1] = g + h0;
        rbase[4 * b + 2] = g + h0 + h1;
        rbase[4 * b + 3] = g + h0 + h1 + h2;
    }
    __syncthreads();

    // stage entries into LDS, slot-ordered
#pragma unroll
    for (int k = 0; k < SC_PPT; ++k) {
        if (brk[2 * k] != 0xFFFFFFFFu) {
            unsigned wb = __float_as_uint(wv[k]);
            unsigned s0 = brk[2 * k] & 255u,     rk0 = brk[2 * k] >> 8;
            unsigned s1 = brk[2 * k + 1] & 255u, rk1 = brk[2 * k + 1] >> 8;
            unsigned l0 = lbase[s0] + rk0;
            unsigned l1 = lbase[s1] + rk1;
            stage[l0] = make_uint2(key[2 * k], wb);
            slotid[l0] = (unsigned char)s0;
            stage[l1] = make_uint2(key[2 * k + 1], wb);
            slotid[l1] = (unsigned char)s1;
        }
    }
    __syncthreads();

    // coalesced writeout: consecutive l -> consecutive global addresses
    const unsigned total = scanbuf[NSLOT - 1];   // inclusive prefix at last slot
    for (unsigned l = threadIdx.x; l < total; l += SC_BLOCK) {
        unsigned s = slotid[l];
        entries[rbase[s] + (l - lbase[s])] = stage[l];
    }
}

// ---------------- Pass B: chunk scan + fused last-block reduce ------------
// FIX: obc = cursors (relative fill); beg = c*cap; after slab write each
//   block bumps done[c]; ticket NSLICES-1 reduces the chunk -> out.
// !FIX: obc = offsets (plain-store prefix); no fusion (chunk_reduce_h).
template<int CHUNK_ATOMS, bool FIX>
__global__ __launch_bounds__(BLOCK) void bucket_scan(
    const float4* __restrict__ charges, const uint2* __restrict__ entries,
    const unsigned* obc, uint2* __restrict__ slabs,
    int natoms, unsigned cap, unsigned* done, float4* out4)
{
    constexpr int PLANE = CHUNK_ATOMS + PLANE_PAD;   // half2s per plane
    extern __shared__ __half2 sm2[];                 // [2][PLANE]
    __half2* smp0 = sm2;                             // ch0,ch1
    __half2* smp1 = sm2 + PLANE;                     // ch2,ch3
    __shared__ unsigned tick;

    const int c  = blockIdx.x / NSLICES;
    const int s  = blockIdx.x - c * NSLICES;
    {
        unsigned* z = (unsigned*)sm2;
        for (int e = threadIdx.x; e < 2 * PLANE; e += BLOCK) z[e] = 0u;
    }
    __syncthreads();

    unsigned beg, cnt;
    if (FIX) {
        beg = (unsigned)c * cap;
        unsigned fill = atomicAdd((unsigned*)obc + c, 0u);  // coherent read
        cnt = min(fill, cap);
    } else {
        beg = obc[c];
        cnt = obc[c + 1] - beg;
    }
    const unsigned e0  = beg + (unsigned)((unsigned long long)cnt * s       / NSLICES);
    const unsigned e1  = beg + (unsigned)((unsigned long long)cnt * (s + 1) / NSLICES);

    auto process = [&](uint2 en) {
        float4 cq = charges[en.x & 0x3FFFFu];
        float w = __uint_as_float(en.y);
        unsigned d = en.x >> 18;
        pkadd(smp0 + d, cq.x * w, cq.y * w);
        pkadd(smp1 + d, cq.z * w, cq.w * w);
    };

    // head: align entry index to even for uint4 loads (beg always even)
    const unsigned e0a = min(e1, (e0 + 1u) & ~1u);
    for (unsigned e = e0 + threadIdx.x; e < e0a; e += BLOCK) process(entries[e]);

    const uint4* ent4 = (const uint4*)entries;
    const unsigned base = e0a >> 1;            // uint4 index
    const unsigned n4   = (e1 - e0a) >> 1;     // number of uint4s (each = 2 entries)
    const unsigned nb   = n4 / (BLOCK * 4);    // 8 entries per thread per batch

    unsigned q = base + threadIdx.x;
    for (unsigned b = 0; b < nb; ++b, q += BLOCK * 4) {
        uint4 E[4];
#pragma unroll
        for (int u = 0; u < 4; ++u) E[u] = ent4[q + u * BLOCK];
        float4 cq[8];
#pragma unroll
        for (int u = 0; u < 4; ++u) {
            cq[2 * u]     = charges[E[u].x & 0x3FFFFu];
            cq[2 * u + 1] = charges[E[u].z & 0x3FFFFu];
        }
#pragma unroll
        for (int u = 0; u < 4; ++u) {
            float w0 = __uint_as_float(E[u].y);
            unsigned d0 = E[u].x >> 18;
            pkadd(smp0 + d0, cq[2 * u].x * w0, cq[2 * u].y * w0);
            pkadd(smp1 + d0, cq[2 * u].z * w0, cq[2 * u].w * w0);
            float w1 = __uint_as_float(E[u].w);
            unsigned d1 = E[u].z >> 18;
            pkadd(smp0 + d1, cq[2 * u + 1].x * w1, cq[2 * u + 1].y * w1);
            pkadd(smp1 + d1, cq[2 * u + 1].z * w1, cq[2 * u + 1].w * w1);
        }
    }
    // uint4 tail
    for (unsigned q2 = base + nb * (BLOCK * 4) + threadIdx.x; q2 < base + n4; q2 += BLOCK) {
        uint4 E = ent4[q2];
        process(make_uint2(E.x, E.y));
        process(make_uint2(E.z, E.w));
    }
    // odd final entry
    for (unsigned e = e0a + 2 * n4 + threadIdx.x; e < e1; e += BLOCK) process(entries[e]);

    // RACE FIX (R18): pkadd's inline-asm DS atomics are untracked by the
    // compiler's waitcnt insertion — drain before the barrier.
    lds_drain();
    __syncthreads();

    // writeout: raw f16 slab, one uint2 (4 ch) per atom — lossless vs LDS
    const int c0 = c * CHUNK_ATOMS;
    const int cn = min(CHUNK_ATOMS, natoms - c0);
    uint2* dst = slabs + (size_t)blockIdx.x * CHUNK_ATOMS;
    for (int a = threadIdx.x; a < cn; a += BLOCK) {
        unsigned b0, b1;
        __builtin_memcpy(&b0, &smp0[a], 4);
        __builtin_memcpy(&b1, &smp1[a], 4);
        dst[a] = make_uint2(b0, b1);
    }

    if constexpr (FIX) {
        // last-arriving block of this chunk reduces its 10 slabs -> out
        __threadfence();                        // release slab writes
        if (threadIdx.x == 0) tick = atomicAdd(&done[c], 1u);
        __syncthreads();
        if (tick == NSLICES - 1) {
            __threadfence();                    // acquire others' slab writes
            const uint2* src = slabs + (size_t)c * NSLICES * CHUNK_ATOMS;
            float4* o = out4 + (size_t)c * CHUNK_ATOMS;
            for (int a = threadIdx.x; a < cn; a += BLOCK) {
                float4 acc = make_float4(0.f, 0.f, 0.f, 0.f);
#pragma unroll
                for (int s2 = 0; s2 < NSLICES; ++s2) {
                    uint2 v = src[(size_t)s2 * CHUNK_ATOMS + a];
                    __half2 h01, h23;
                    __builtin_memcpy(&h01, &v.x, 4);
                    __builtin_memcpy(&h23, &v.y, 4);
                    float2 f01 = __half22float2(h01);
                    float2 f23 = __half22float2(h23);
                    acc.x += f01.x; acc.y += f01.y; acc.z += f23.x; acc.w += f23.y;
                }
                o[a] = acc;
            }
        }
    }
}

// ---------------- slab reduce: f16 slabs -> f32 out (fallback only) -------
template<int CH_ATOMS, int NS>
__global__ __launch_bounds__(256) void chunk_reduce_h(
    const uint2* __restrict__ ws, float4* __restrict__ out, int natoms_total)
{
    int g = blockIdx.x * blockDim.x + threadIdx.x;
    if (g >= natoms_total) return;
    int c = g / CH_ATOMS;
    int local = g - c * CH_ATOMS;
    const uint2* p = ws + ((size_t)c * NS) * CH_ATOMS + local;
    float4 acc = make_float4(0.f, 0.f, 0.f, 0.f);
#pragma unroll
    for (int s = 0; s < NS; ++s) {
        uint2 v = p[(size_t)s * CH_ATOMS];
        __half2 h01, h23;
        __builtin_memcpy(&h01, &v.x, 4);
        __builtin_memcpy(&h23, &v.y, 4);
        float2 f01 = __half22float2(h01);
        float2 f23 = __half22float2(h23);
        acc.x += f01.x; acc.y += f01.y; acc.z += f23.x; acc.w += f23.y;
    }
    out[g] = acc;
}

// ---------------- slab reduce (f32, chunk_scan fallback only) --------------
template<int CH_ELEMS, int NS>
__global__ __launch_bounds__(256) void chunk_reduce(
    const float4* __restrict__ ws, float4* __restrict__ out, int total4)
{
    int g = blockIdx.x * blockDim.x + threadIdx.x;
    if (g >= total4) return;
    constexpr int CH4 = CH_ELEMS / 4;
    int c = g / CH4;
    int local = g - c * CH4;
    const float4* p = ws + ((size_t)c * NS) * CH4 + local;
    float4 acc = make_float4(0.f, 0.f, 0.f, 0.f);
#pragma unroll
    for (int s = 0; s < NS; ++s) {
        float4 v = p[(size_t)s * CH4];
        acc.x += v.x; acc.y += v.y; acc.z += v.z; acc.w += v.w;
    }
    out[g] = acc;
}

// ---------------- Fallback (R3): redundant chunk scan ----------------
template<int CHUNK_ATOMS, bool USE_WS>
__global__ __launch_bounds__(BLOCK) void chunk_scan(
    const float4* __restrict__ charges, const int2* __restrict__ idx,
    const float* __restrict__ dist, float* __restrict__ dest,
    int npairs, int natoms)
{
    constexpr int CH_ELEMS = CHUNK_ATOMS * 4;
    extern __shared__ float sm[];
    const int c  = blockIdx.x / FB_NSL;
    const int s  = blockIdx.x - c * FB_NSL;
    const int c0 = c * CHUNK_ATOMS;
    const int cn = min(CHUNK_ATOMS, natoms - c0);
    for (int e = threadIdx.x; e < CH_ELEMS; e += BLOCK) sm[e] = 0.f;
    __syncthreads();
    const int p0 = (int)((long long)npairs * s       / FB_NSL);
    const int p1 = (int)((long long)npairs * (s + 1) / FB_NSL);
    const int nbatch = (p1 - p0) / (BLOCK * FB_UNROLL);
    int p = p0 + threadIdx.x;
    for (int b = 0; b < nbatch; ++b, p += BLOCK * FB_UNROLL) {
        int2 ij[FB_UNROLL]; float dd[FB_UNROLL];
#pragma unroll
        for (int u = 0; u < FB_UNROLL; ++u) { ij[u] = idx[p + u * BLOCK]; dd[u] = dist[p + u * BLOCK]; }
#pragma unroll
        for (int u = 0; u < FB_UNROLL; ++u) {
            unsigned li = (unsigned)(ij[u].x - c0), lj = (unsigned)(ij[u].y - c0);
            float w = 0.5f / dd[u];
            if (li < (unsigned)cn) {
                float4 cq = charges[ij[u].y]; float* bp = sm + li * 4;
                fadd(bp + 0, cq.x * w); fadd(bp + 1, cq.y * w);
                fadd(bp + 2, cq.z * w); fadd(bp + 3, cq.w * w);
            }
            if (lj < (unsigned)cn) {
                float4 cq = charges[ij[u].x]; float* bp = sm + lj * 4;
                fadd(bp + 0, cq.x * w); fadd(bp + 1, cq.y * w);
                fadd(bp + 2, cq.z * w); fadd(bp + 3, cq.w * w);
            }
        }
    }
    for (; p < p1; p += BLOCK) {
        int2 ij = idx[p];
        unsigned li = (unsigned)(ij.x - c0), lj = (unsigned)(ij.y - c0);
        if (li < (unsigned)cn || lj < (unsigned)cn) {
            float w = 0.5f / dist[p];
            if (li < (unsigned)cn) {
                float4 cq = charges[ij.y]; float* bp = sm + li * 4;
                fadd(bp + 0, cq.x * w); fadd(bp + 1, cq.y * w);
                fadd(bp + 2, cq.z * w); fadd(bp + 3, cq.w * w);
            }
            if (lj < (unsigned)cn) {
                float4 cq = charges[ij.x]; float* bp = sm + lj * 4;
                fadd(bp + 0, cq.x * w); fadd(bp + 1, cq.y * w);
                fadd(bp + 2, cq.z * w); fadd(bp + 3, cq.w * w);
            }
        }
    }
    __syncthreads();
    const int nvalid = cn * 4;
    if (USE_WS) {
        float* dst = dest + (size_t)blockIdx.x * CH_ELEMS;
        for (int e = threadIdx.x; e < nvalid; e += BLOCK) dst[e] = sm[e];
    } else {
        float* dst = dest + (size_t)c0 * 4;
        for (int e = threadIdx.x; e < nvalid; e += BLOCK) fadd(dst + e, sm[e]);
    }
}

extern "C" void kernel_launch(void* const* d_in, const int* in_sizes, int n_in,
                              void* d_out, int out_size, void* d_ws, size_t ws_size,
                              hipStream_t stream) {
    const float4* charges = (const float4*)d_in[0];
    const int2*   idx     = (const int2*)  d_in[1];
    const float*  dist    = (const float*) d_in[2];
    float*        out     = (float*)d_out;

    const int natoms = in_sizes[0] / 4;     // 200000
    const int npairs = in_sizes[2];         // 8000000
    const int total  = out_size;            // 800000

    int dev = 0;
    hipGetDevice(&dev);
    int maxShm = 0;
    hipDeviceGetAttribute(&maxShm, hipDeviceAttributeMaxSharedMemoryPerBlock, dev);
    const bool big = (maxShm >= 65536);

    constexpr int CA = 4096, CE = CA * 4;
    const int C    = (natoms + CA - 1) / CA;       // 49
    const int grid = C * NSLICES;                  // 490
    const size_t scan_shm = (size_t)2 * (CA + PLANE_PAD) * sizeof(__half2); // ~33 KB

    const size_t ENT_OFF     = 1024;
    const size_t slabh_bytes = (size_t)grid * CA * sizeof(uint2);    // 16.06 MB
    const int sc_grid = (npairs + SC_BLOCK * SC_PPT - 1) / (SC_BLOCK * SC_PPT);
    const bool shape_ok = big && natoms <= (1 << 18) && C == NCHUNK
                          && (total & 3) == 0 && total == 4 * natoms;

    // ---- FIX path capacity from ws (mean 327,680 + >=30 sigma required)
    unsigned capb = 0;
    if (ws_size > ENT_OFF + slabh_bytes + 256) {
        size_t cmax = (ws_size - ENT_OFF - slabh_bytes - 256) / ((size_t)NCHUNK * sizeof(uint2));
        capb = (unsigned)((cmax > 480000) ? 480000 : cmax);
        capb &= ~63u;                         // even/64-aligned bucket bases
    }
    const bool fix_ok = shape_ok && capb >= CAP_MIN;

    const size_t ent_bytes_old = (size_t)2 * npairs * sizeof(uint2);  // 128 MB
    const size_t slab_off_old  = (ENT_OFF + ent_bytes_old + 255) & ~(size_t)255;
    const bool old_ok = shape_ok && ws_size >= slab_off_old + slabh_bytes;

    if (fix_ok) {
        unsigned* cursors = (unsigned*)((char*)d_ws + 512);   // [49] relative
        unsigned* done    = (unsigned*)((char*)d_ws + 768);   // [49]
        uint2*    entries = (uint2*)((char*)d_ws + ENT_OFF);
        const size_t slab_off = (ENT_OFF + (size_t)NCHUNK * capb * sizeof(uint2) + 255) & ~(size_t)255;
        uint2*    slabs   = (uint2*)((char*)d_ws + slab_off);

        hipMemsetAsync(d_ws, 0, 1024, stream);   // zeroes cursors + done
        bucket_scatter<true><<<sc_grid, SC_BLOCK, 0, stream>>>(
            idx, dist, entries, cursors, npairs, capb);
        hipFuncSetAttribute((const void*)bucket_scan<CA, true>,
                            hipFuncAttributeMaxDynamicSharedMemorySize, (int)scan_shm);
        bucket_scan<CA, true><<<grid, BLOCK, scan_shm, stream>>>(
            charges, entries, cursors, slabs, natoms, capb, done, (float4*)out);
    } else if (old_ok) {
        unsigned* counts  = (unsigned*)d_ws;               // [49]
        unsigned* offsets = (unsigned*)((char*)d_ws + 256);// [50]
        unsigned* cursors = (unsigned*)((char*)d_ws + 512);// [49]
        uint2*    entries = (uint2*)((char*)d_ws + ENT_OFF);
        uint2*    slabs   = (uint2*)((char*)d_ws + slab_off_old);

        hipMemsetAsync(d_ws, 0, 1024, stream);
        bucket_count<<<1024, CT_BLOCK, 0, stream>>>((const int4*)idx, counts, npairs);
        bucket_prefix<<<1, 32, 0, stream>>>(counts, offsets, cursors, C);
        bucket_scatter<false><<<sc_grid, SC_BLOCK, 0, stream>>>(
            idx, dist, entries, cursors, npairs, 0u);
        hipFuncSetAttribute((const void*)bucket_scan<CA, false>,
                            hipFuncAttributeMaxDynamicSharedMemorySize, (int)scan_shm);
        bucket_scan<CA, false><<<grid, BLOCK, scan_shm, stream>>>(
            charges, entries, offsets, slabs, natoms, 0u, nullptr, nullptr);
        chunk_reduce_h<CA, NSLICES><<<(natoms + 255) / 256, 256, 0, stream>>>(
            slabs, (float4*)out, natoms);
    } else if (big) {
        const size_t ws_need = (size_t)grid * CE * sizeof(float);
        if (ws_size >= ws_need && (total & 3) == 0) {
            hipFuncSetAttribute((const void*)chunk_scan<CA, true>,
                                hipFuncAttributeMaxDynamicSharedMemorySize, CE * 4);
            chunk_scan<CA, true><<<grid, BLOCK, CE * 4, stream>>>(
                charges, idx, dist, (float*)d_ws, npairs, natoms);
            chunk_reduce<CE, FB_NSL><<<(total / 4 + 255) / 256, 256, 0, stream>>>(
                (const float4*)d_ws, (float4*)out, total / 4);
        } else {
            hipMemsetAsync(d_out, 0, (size_t)total * sizeof(float), stream);
            hipFuncSetAttribute((const void*)chunk_scan<CA, false>,
                                hipFuncAttributeMaxDynamicSharedMemorySize, CE * 4);
            chunk_scan<CA, false><<<grid, BLOCK, CE * 4, stream>>>(
                charges, idx, dist, out, npairs, natoms);
        }
    } else {
        constexpr int CA2 = 2048, CE2 = CA2 * 4;
        const int C2 = (natoms + CA2 - 1) / CA2;
        const int grid2 = C2 * FB_NSL;
        const size_t ws_need = (size_t)grid2 * CE2 * sizeof(float);
        if (ws_size >= ws_need && (total & 3) == 0) {
            chunk_scan<CA2, true><<<grid2, BLOCK, CE2 * 4, stream>>>(
                charges, idx, dist, (float*)d_ws, npairs, natoms);
            chunk_reduce<CE2, FB_NSL><<<(total / 4 + 255) / 256, 256, 0, stream>>>(
                (const float4*)d_ws, (float4*)out, total / 4);
        } else {
            hipMemsetAsync(d_out, 0, (size_t)total * sizeof(float), stream);
            chunk_scan<CA2, false><<<grid2, BLOCK, CE2 * 4, stream>>>(
                charges, idx, dist, out, npairs, natoms);
        }
    }
}

// Round 14
// 372.001 us; speedup vs baseline: 1.6558x; 1.6558x over previous
//
#include <hip/hip_runtime.h>
#include <hip/hip_fp16.h>

// Round 21: REVERT to R19 exactly (373.8us PASS). R20's fused last-block
//   reduce regressed 374->616: per-block __threadfence() (required for
//   cross-XCD slab visibility) emits L2 writeback/invalidate; 490 of them
//   thrash the L2 the gather path depends on (scan 182->470us, VALUBusy
//   2.7->1.15%). The fence cost is inherent to that fusion -> abandoned.
//   R19 structure: cursor_init -> scatter(FIX) -> scan(FIX) -> reduce;
//   fixed-capacity buckets (capb >= mean+30sigma, clamp as safety net);
//   packed-f16 LDS atomics (ds_pk_add_f16 inline asm) + lgkmcnt drain
//   before the final barrier (R18 race fix); f16 slabs; LDS-staged
//   coalesced scatter writes.
// Entry = (other_idx(18b) | dest_local(12b)<<18, w=0.5/d).

#define BLOCK 1024
#define NSLICES 10
#define CT_BLOCK 256
#define SC_BLOCK 256
#define SC_PPT 8
#define SC_NENT (SC_BLOCK * SC_PPT * 2)   // 4096 entries staged per block
#define CA_BITS 12        // chunk = 4096 atoms
#define NCHUNK 49
#define NSLOT (NCHUNK * 4)                // 196
#define PLANE_PAD 16      // half2s; plane1 bank offset +16
#define CAP_MIN 345024u   // 327,680 mean + ~30 sigma, 64-aligned
#define FB_NSL 10
#define FB_UNROLL 8

__device__ __forceinline__ void fadd(float* p, float v) {
#if defined(__HIP_DEVICE_COMPILE__)
    unsafeAtomicAdd(p, v);
#else
    atomicAdd(p, v);
#endif
}

// Native packed-f16 LDS atomic add (no return), via inline asm.
// NOTE: invisible to compiler waitcnt tracking — every kernel using this
// MUST execute lds_drain() before a barrier whose consumers read the cells.
__device__ __forceinline__ void pkadd(__half2* p, float lo, float hi) {
#if defined(__HIP_DEVICE_COMPILE__)
    __half2 v = __float22half2_rn(make_float2(lo, hi));
    unsigned bits;
    __builtin_memcpy(&bits, &v, 4);
    unsigned off = (unsigned)(unsigned long long)(void*)p;
    asm volatile("ds_pk_add_f16 %0, %1" :: "v"(off), "v"(bits) : "memory");
#else
    (void)p; (void)lo; (void)hi;
#endif
}

__device__ __forceinline__ void lds_drain() {
#if defined(__HIP_DEVICE_COMPILE__)
    asm volatile("s_waitcnt lgkmcnt(0)" ::: "memory");
#endif
}

// ---------------- cursor init (FIX path): cursors[b] = b*cap ---------------
__global__ void cursor_init(unsigned* __restrict__ cursors, unsigned cap)
{
    int b = threadIdx.x;
    if (b < NCHUNK) cursors[b] = (unsigned)b * cap;
}

// ---------------- Pass 0 (fallback only): count via private LDS hists -----
__global__ __launch_bounds__(CT_BLOCK) void bucket_count(
    const int4* __restrict__ idx2, unsigned* __restrict__ counts, int npairs)
{
    __shared__ unsigned ph[CT_BLOCK * NCHUNK];   // 50.2 KB, thread-major
    unsigned* mine = ph + threadIdx.x * NCHUNK;
#pragma unroll
    for (int b = 0; b < NCHUNK; ++b) mine[b] = 0;
    __syncthreads();

    const int n4 = npairs >> 1;                  // int4 = 2 pairs
    const int stride = gridDim.x * CT_BLOCK;
    for (int q = blockIdx.x * CT_BLOCK + threadIdx.x; q < n4; q += stride) {
        int4 v = idx2[q];
        ++mine[(unsigned)v.x >> CA_BITS];
        ++mine[(unsigned)v.y >> CA_BITS];
        ++mine[(unsigned)v.z >> CA_BITS];
        ++mine[(unsigned)v.w >> CA_BITS];
    }
    if ((npairs & 1) && blockIdx.x == 0 && threadIdx.x == 0) {
        const int2* idx = (const int2*)idx2;
        int2 ij = idx[npairs - 1];
        ++mine[(unsigned)ij.x >> CA_BITS];
        ++mine[(unsigned)ij.y >> CA_BITS];
    }
    __syncthreads();

    for (int b = threadIdx.x; b < NCHUNK; b += CT_BLOCK) {
        unsigned s = 0;
#pragma unroll 8
        for (int t = 0; t < CT_BLOCK; ++t) s += ph[t * NCHUNK + b];
        if (s) atomicAdd(&counts[b], s);
    }
}

// ---------------- prefix sum (fallback only) ----------------
__global__ void bucket_prefix(const unsigned* __restrict__ counts,
                              unsigned* __restrict__ offsets,
                              unsigned* __restrict__ cursors, int nbuckets)
{
    if (threadIdx.x == 0 && blockIdx.x == 0) {
        unsigned acc = 0;
        for (int b = 0; b < nbuckets; ++b) {
            offsets[b] = acc; cursors[b] = acc; acc += counts[b];
        }
        offsets[nbuckets] = acc;
    }
}

// ---------------- Pass A: scatter, LDS-staged for coalesced writes --------
template<bool FIX>
__global__ __launch_bounds__(SC_BLOCK) void bucket_scatter(
    const int2*  __restrict__ idx, const float* __restrict__ dist,
    uint2* __restrict__ entries, unsigned* __restrict__ cursors, int npairs,
    unsigned cap)
{
    __shared__ unsigned hist[NSLOT];          // per-slot counts
    __shared__ unsigned lbase[NSLOT];         // exclusive local prefix
    __shared__ unsigned rbase[NSLOT];         // global base per slot
    __shared__ unsigned scanbuf[SC_BLOCK];
    __shared__ uint2    stage[SC_NENT];       // 32 KB
    __shared__ unsigned char slotid[SC_NENT]; // 4 KB
    for (int b = threadIdx.x; b < NSLOT; b += SC_BLOCK) hist[b] = 0;
    __syncthreads();

    const int p0 = blockIdx.x * (SC_BLOCK * SC_PPT) + threadIdx.x;
    const unsigned r = threadIdx.x & 3;
    unsigned key[2 * SC_PPT];
    unsigned brk[2 * SC_PPT];       // slot(8b: b*4+r) | rank<<8
    float    wv[SC_PPT];

#pragma unroll
    for (int k = 0; k < SC_PPT; ++k) {
        int p = p0 + k * SC_BLOCK;
        if (p < npairs) {
            int2 ij = idx[p];
            wv[k] = 0.5f / dist[p];
            unsigned s0 = (((unsigned)ij.x >> CA_BITS) << 2) + r;
            unsigned s1 = (((unsigned)ij.y >> CA_BITS) << 2) + r;
            key[2 * k]     = (unsigned)ij.y | (((unsigned)ij.x & ((1u << CA_BITS) - 1)) << 18);
            brk[2 * k]     = s0 | (atomicAdd(&hist[s0], 1u) << 8);
            key[2 * k + 1] = (unsigned)ij.x | (((unsigned)ij.y & ((1u << CA_BITS) - 1)) << 18);
            brk[2 * k + 1] = s1 | (atomicAdd(&hist[s1], 1u) << 8);
        } else {
            brk[2 * k] = brk[2 * k + 1] = 0xFFFFFFFFu;
        }
    }
    __syncthreads();

    // exclusive prefix over 196 slot counts (block Hillis-Steele, 256 wide)
    {
        const int t = threadIdx.x;
        unsigned v = (t < NSLOT) ? hist[t] : 0u;
        scanbuf[t] = v;
        __syncthreads();
        for (int off = 1; off < SC_BLOCK; off <<= 1) {
            unsigned x = (t >= off) ? scanbuf[t - off] : 0u;
            __syncthreads();
            scanbuf[t] += x;
            __syncthreads();
        }
        if (t < NSLOT) lbase[t] = scanbuf[t] - v;   // exclusive prefix
    }
    // global reservation per bucket (replica-ordered)
    if (threadIdx.x < NCHUNK) {
        int b = threadIdx.x;
        unsigned h0 = hist[4 * b], h1 = hist[4 * b + 1], h2 = hist[4 * b + 2], h3 = hist[4 * b + 3];
        unsigned tot = h0 + h1 + h2 + h3;
        unsigned g = tot ? atomicAdd(&cursors[b], tot) : 0u;
        if (FIX && tot) {
            // memory-safety clamp; capb slack >= 30 sigma so never triggers
            unsigned lim = (unsigned)(b + 1) * cap;
            if (g + tot > lim) g = lim - tot;
        }
        rbase[4 * b]     = g;
        rbase[4 * b + 1] = g + h0;
        rbase[4 * b + 2] = g + h0 + h1;
        rbase[4 * b + 3] = g + h0 + h1 + h2;
    }
    __syncthreads();

    // stage entries into LDS, slot-ordered
#pragma unroll
    for (int k = 0; k < SC_PPT; ++k) {
        if (brk[2 * k] != 0xFFFFFFFFu) {
            unsigned wb = __float_as_uint(wv[k]);
            unsigned s0 = brk[2 * k] & 255u,     rk0 = brk[2 * k] >> 8;
            unsigned s1 = brk[2 * k + 1] & 255u, rk1 = brk[2 * k + 1] >> 8;
            unsigned l0 = lbase[s0] + rk0;
            unsigned l1 = lbase[s1] + rk1;
            stage[l0] = make_uint2(key[2 * k], wb);
            slotid[l0] = (unsigned char)s0;
            stage[l1] = make_uint2(key[2 * k + 1], wb);
            slotid[l1] = (unsigned char)s1;
        }
    }
    __syncthreads();

    // coalesced writeout: consecutive l -> consecutive global addresses
    const unsigned total = scanbuf[NSLOT - 1];   // inclusive prefix at last slot
    for (unsigned l = threadIdx.x; l < total; l += SC_BLOCK) {
        unsigned s = slotid[l];
        entries[rbase[s] + (l - lbase[s])] = stage[l];
    }
}

// ---------------- Pass B: chunk scan, packed-f16 LDS accumulation ----------
// FIX: obc = cursors (post-scatter); beg = c*cap; fill via coherent atomic.
// !FIX: obc = offsets (plain-store prefix).
// Slab output: raw f16, uint2 per atom = (half2 ch01, half2 ch23).
template<int CHUNK_ATOMS, bool FIX>
__global__ __launch_bounds__(BLOCK) void bucket_scan(
    const float4* __restrict__ charges, const uint2* __restrict__ entries,
    const unsigned* obc, uint2* __restrict__ slabs,
    int natoms, unsigned cap)
{
    constexpr int PLANE = CHUNK_ATOMS + PLANE_PAD;   // half2s per plane
    extern __shared__ __half2 sm2[];                 // [2][PLANE]
    __half2* smp0 = sm2;                             // ch0,ch1
    __half2* smp1 = sm2 + PLANE;                     // ch2,ch3

    const int c  = blockIdx.x / NSLICES;
    const int s  = blockIdx.x - c * NSLICES;
    {
        unsigned* z = (unsigned*)sm2;
        for (int e = threadIdx.x; e < 2 * PLANE; e += BLOCK) z[e] = 0u;
    }
    __syncthreads();

    unsigned beg, cnt;
    if (FIX) {
        beg = (unsigned)c * cap;
        unsigned cur = atomicAdd((unsigned*)obc + c, 0u);  // coherent read
        cnt = min(cur - beg, cap);
    } else {
        beg = obc[c];
        cnt = obc[c + 1] - beg;
    }
    const unsigned e0  = beg + (unsigned)((unsigned long long)cnt * s       / NSLICES);
    const unsigned e1  = beg + (unsigned)((unsigned long long)cnt * (s + 1) / NSLICES);

    auto process = [&](uint2 en) {
        float4 cq = charges[en.x & 0x3FFFFu];
        float w = __uint_as_float(en.y);
        unsigned d = en.x >> 18;
        pkadd(smp0 + d, cq.x * w, cq.y * w);
        pkadd(smp1 + d, cq.z * w, cq.w * w);
    };

    // head: align entry index to even for uint4 loads (beg always even)
    const unsigned e0a = min(e1, (e0 + 1u) & ~1u);
    for (unsigned e = e0 + threadIdx.x; e < e0a; e += BLOCK) process(entries[e]);

    const uint4* ent4 = (const uint4*)entries;
    const unsigned base = e0a >> 1;            // uint4 index
    const unsigned n4   = (e1 - e0a) >> 1;     // number of uint4s (each = 2 entries)
    const unsigned nb   = n4 / (BLOCK * 4);    // 8 entries per thread per batch

    unsigned q = base + threadIdx.x;
    for (unsigned b = 0; b < nb; ++b, q += BLOCK * 4) {
        uint4 E[4];
#pragma unroll
        for (int u = 0; u < 4; ++u) E[u] = ent4[q + u * BLOCK];
        float4 cq[8];
#pragma unroll
        for (int u = 0; u < 4; ++u) {
            cq[2 * u]     = charges[E[u].x & 0x3FFFFu];
            cq[2 * u + 1] = charges[E[u].z & 0x3FFFFu];
        }
#pragma unroll
        for (int u = 0; u < 4; ++u) {
            float w0 = __uint_as_float(E[u].y);
            unsigned d0 = E[u].x >> 18;
            pkadd(smp0 + d0, cq[2 * u].x * w0, cq[2 * u].y * w0);
            pkadd(smp1 + d0, cq[2 * u].z * w0, cq[2 * u].w * w0);
            float w1 = __uint_as_float(E[u].w);
            unsigned d1 = E[u].z >> 18;
            pkadd(smp0 + d1, cq[2 * u + 1].x * w1, cq[2 * u + 1].y * w1);
            pkadd(smp1 + d1, cq[2 * u + 1].z * w1, cq[2 * u + 1].w * w1);
        }
    }
    // uint4 tail
    for (unsigned q2 = base + nb * (BLOCK * 4) + threadIdx.x; q2 < base + n4; q2 += BLOCK) {
        uint4 E = ent4[q2];
        process(make_uint2(E.x, E.y));
        process(make_uint2(E.z, E.w));
    }
    // odd final entry
    for (unsigned e = e0a + 2 * n4 + threadIdx.x; e < e1; e += BLOCK) process(entries[e]);

    // RACE FIX (R18): pkadd's inline-asm DS atomics are untracked by the
    // compiler's waitcnt insertion — drain before the barrier.
    lds_drain();
    __syncthreads();

    // writeout: raw f16 slab, one uint2 (4 ch) per atom — lossless vs LDS
    const int c0 = c * CHUNK_ATOMS;
    const int cn = min(CHUNK_ATOMS, natoms - c0);
    uint2* dst = slabs + (size_t)blockIdx.x * CHUNK_ATOMS;
    for (int a = threadIdx.x; a < cn; a += BLOCK) {
        unsigned b0, b1;
        __builtin_memcpy(&b0, &smp0[a], 4);
        __builtin_memcpy(&b1, &smp1[a], 4);
        dst[a] = make_uint2(b0, b1);
    }
}

// ---------------- slab reduce: f16 slabs -> f32 out ----------------
template<int CH_ATOMS, int NS>
__global__ __launch_bounds__(256) void chunk_reduce_h(
    const uint2* __restrict__ ws, float4* __restrict__ out, int natoms_total)
{
    int g = blockIdx.x * blockDim.x + threadIdx.x;
    if (g >= natoms_total) return;
    int c = g / CH_ATOMS;
    int local = g - c * CH_ATOMS;
    const uint2* p = ws + ((size_t)c * NS) * CH_ATOMS + local;
    float4 acc = make_float4(0.f, 0.f, 0.f, 0.f);
#pragma unroll
    for (int s = 0; s < NS; ++s) {
        uint2 v = p[(size_t)s * CH_ATOMS];
        __half2 h01, h23;
        __builtin_memcpy(&h01, &v.x, 4);
        __builtin_memcpy(&h23, &v.y, 4);
        float2 f01 = __half22float2(h01);
        float2 f23 = __half22float2(h23);
        acc.x += f01.x; acc.y += f01.y; acc.z += f23.x; acc.w += f23.y;
    }
    out[g] = acc;
}

// ---------------- slab reduce (f32, chunk_scan fallback only) --------------
template<int CH_ELEMS, int NS>
__global__ __launch_bounds__(256) void chunk_reduce(
    const float4* __restrict__ ws, float4* __restrict__ out, int total4)
{
    int g = blockIdx.x * blockDim.x + threadIdx.x;
    if (g >= total4) return;
    constexpr int CH4 = CH_ELEMS / 4;
    int c = g / CH4;
    int local = g - c * CH4;
    const float4* p = ws + ((size_t)c * NS) * CH4 + local;
    float4 acc = make_float4(0.f, 0.f, 0.f, 0.f);
#pragma unroll
    for (int s = 0; s < NS; ++s) {
        float4 v = p[(size_t)s * CH4];
        acc.x += v.x; acc.y += v.y; acc.z += v.z; acc.w += v.w;
    }
    out[g] = acc;
}

// ---------------- Fallback (R3): redundant chunk scan ----------------
template<int CHUNK_ATOMS, bool USE_WS>
__global__ __launch_bounds__(BLOCK) void chunk_scan(
    const float4* __restrict__ charges, const int2* __restrict__ idx,
    const float* __restrict__ dist, float* __restrict__ dest,
    int npairs, int natoms)
{
    constexpr int CH_ELEMS = CHUNK_ATOMS * 4;
    extern __shared__ float sm[];
    const int c  = blockIdx.x / FB_NSL;
    const int s  = blockIdx.x - c * FB_NSL;
    const int c0 = c * CHUNK_ATOMS;
    const int cn = min(CHUNK_ATOMS, natoms - c0);
    for (int e = threadIdx.x; e < CH_ELEMS; e += BLOCK) sm[e] = 0.f;
    __syncthreads();
    const int p0 = (int)((long long)npairs * s       / FB_NSL);
    const int p1 = (int)((long long)npairs * (s + 1) / FB_NSL);
    const int nbatch = (p1 - p0) / (BLOCK * FB_UNROLL);
    int p = p0 + threadIdx.x;
    for (int b = 0; b < nbatch; ++b, p += BLOCK * FB_UNROLL) {
        int2 ij[FB_UNROLL]; float dd[FB_UNROLL];
#pragma unroll
        for (int u = 0; u < FB_UNROLL; ++u) { ij[u] = idx[p + u * BLOCK]; dd[u] = dist[p + u * BLOCK]; }
#pragma unroll
        for (int u = 0; u < FB_UNROLL; ++u) {
            unsigned li = (unsigned)(ij[u].x - c0), lj = (unsigned)(ij[u].y - c0);
            float w = 0.5f / dd[u];
            if (li < (unsigned)cn) {
                float4 cq = charges[ij[u].y]; float* bp = sm + li * 4;
                fadd(bp + 0, cq.x * w); fadd(bp + 1, cq.y * w);
                fadd(bp + 2, cq.z * w); fadd(bp + 3, cq.w * w);
            }
            if (lj < (unsigned)cn) {
                float4 cq = charges[ij[u].x]; float* bp = sm + lj * 4;
                fadd(bp + 0, cq.x * w); fadd(bp + 1, cq.y * w);
                fadd(bp + 2, cq.z * w); fadd(bp + 3, cq.w * w);
            }
        }
    }
    for (; p < p1; p += BLOCK) {
        int2 ij = idx[p];
        unsigned li = (unsigned)(ij.x - c0), lj = (unsigned)(ij.y - c0);
        if (li < (unsigned)cn || lj < (unsigned)cn) {
            float w = 0.5f / dist[p];
            if (li < (unsigned)cn) {
                float4 cq = charges[ij.y]; float* bp = sm + li * 4;
                fadd(bp + 0, cq.x * w); fadd(bp + 1, cq.y * w);
                fadd(bp + 2, cq.z * w); fadd(bp + 3, cq.w * w);
            }
            if (lj < (unsigned)cn) {
                float4 cq = charges[ij.x]; float* bp = sm + lj * 4;
                fadd(bp + 0, cq.x * w); fadd(bp + 1, cq.y * w);
                fadd(bp + 2, cq.z * w); fadd(bp + 3, cq.w * w);
            }
        }
    }
    __syncthreads();
    const int nvalid = cn * 4;
    if (USE_WS) {
        float* dst = dest + (size_t)blockIdx.x * CH_ELEMS;
        for (int e = threadIdx.x; e < nvalid; e += BLOCK) dst[e] = sm[e];
    } else {
        float* dst = dest + (size_t)c0 * 4;
        for (int e = threadIdx.x; e < nvalid; e += BLOCK) fadd(dst + e, sm[e]);
    }
}

extern "C" void kernel_launch(void* const* d_in, const int* in_sizes, int n_in,
                              void* d_out, int out_size, void* d_ws, size_t ws_size,
                              hipStream_t stream) {
    const float4* charges = (const float4*)d_in[0];
    const int2*   idx     = (const int2*)  d_in[1];
    const float*  dist    = (const float*) d_in[2];
    float*        out     = (float*)d_out;

    const int natoms = in_sizes[0] / 4;     // 200000
    const int npairs = in_sizes[2];         // 8000000
    const int total  = out_size;            // 800000

    int dev = 0;
    hipGetDevice(&dev);
    int maxShm = 0;
    hipDeviceGetAttribute(&maxShm, hipDeviceAttributeMaxSharedMemoryPerBlock, dev);
    const bool big = (maxShm >= 65536);

    constexpr int CA = 4096, CE = CA * 4;
    const int C    = (natoms + CA - 1) / CA;       // 49
    const int grid = C * NSLICES;                  // 490
    const size_t scan_shm = (size_t)2 * (CA + PLANE_PAD) * sizeof(__half2); // ~33 KB

    const size_t ENT_OFF     = 1024;
    const size_t slabh_bytes = (size_t)grid * CA * sizeof(uint2);    // 16.06 MB
    const int sc_grid = (npairs + SC_BLOCK * SC_PPT - 1) / (SC_BLOCK * SC_PPT);
    const bool shape_ok = big && natoms <= (1 << 18) && C == NCHUNK
                          && (total & 3) == 0 && total == 4 * natoms;

    // ---- FIX path capacity from ws (mean 327,680 + >=30 sigma required)
    unsigned capb = 0;
    if (ws_size > ENT_OFF + slabh_bytes + 256) {
        size_t cmax = (ws_size - ENT_OFF - slabh_bytes - 256) / ((size_t)NCHUNK * sizeof(uint2));
        capb = (unsigned)((cmax > 480000) ? 480000 : cmax);
        capb &= ~63u;                         // even/64-aligned bucket bases
    }
    const bool fix_ok = shape_ok && capb >= CAP_MIN;

    const size_t ent_bytes_old = (size_t)2 * npairs * sizeof(uint2);  // 128 MB
    const size_t slab_off_old  = (ENT_OFF + ent_bytes_old + 255) & ~(size_t)255;
    const bool old_ok = shape_ok && ws_size >= slab_off_old + slabh_bytes;

    if (fix_ok) {
        unsigned* cursors = (unsigned*)((char*)d_ws + 512);
        uint2*    entries = (uint2*)((char*)d_ws + ENT_OFF);
        const size_t slab_off = (ENT_OFF + (size_t)NCHUNK * capb * sizeof(uint2) + 255) & ~(size_t)255;
        uint2*    slabs   = (uint2*)((char*)d_ws + slab_off);

        cursor_init<<<1, 64, 0, stream>>>(cursors, capb);
        bucket_scatter<true><<<sc_grid, SC_BLOCK, 0, stream>>>(
            idx, dist, entries, cursors, npairs, capb);
        hipFuncSetAttribute((const void*)bucket_scan<CA, true>,
                            hipFuncAttributeMaxDynamicSharedMemorySize, (int)scan_shm);
        bucket_scan<CA, true><<<grid, BLOCK, scan_shm, stream>>>(
            charges, entries, cursors, slabs, natoms, capb);
        chunk_reduce_h<CA, NSLICES><<<(natoms + 255) / 256, 256, 0, stream>>>(
            slabs, (float4*)out, natoms);
    } else if (old_ok) {
        unsigned* counts  = (unsigned*)d_ws;               // [49]
        unsigned* offsets = (unsigned*)((char*)d_ws + 256);// [50]
        unsigned* cursors = (unsigned*)((char*)d_ws + 512);// [49]
        uint2*    entries = (uint2*)((char*)d_ws + ENT_OFF);
        uint2*    slabs   = (uint2*)((char*)d_ws + slab_off_old);

        hipMemsetAsync(d_ws, 0, 1024, stream);
        bucket_count<<<1024, CT_BLOCK, 0, stream>>>((const int4*)idx, counts, npairs);
        bucket_prefix<<<1, 32, 0, stream>>>(counts, offsets, cursors, C);
        bucket_scatter<false><<<sc_grid, SC_BLOCK, 0, stream>>>(
            idx, dist, entries, cursors, npairs, 0u);
        hipFuncSetAttribute((const void*)bucket_scan<CA, false>,
                            hipFuncAttributeMaxDynamicSharedMemorySize, (int)scan_shm);
        bucket_scan<CA, false><<<grid, BLOCK, scan_shm, stream>>>(
            charges, entries, offsets, slabs, natoms, 0u);
        chunk_reduce_h<CA, NSLICES><<<(natoms + 255) / 256, 256, 0, stream>>>(
            slabs, (float4*)out, natoms);
    } else if (big) {
        const size_t ws_need = (size_t)grid * CE * sizeof(float);
        if (ws_size >= ws_need && (total & 3) == 0) {
            hipFuncSetAttribute((const void*)chunk_scan<CA, true>,
                                hipFuncAttributeMaxDynamicSharedMemorySize, CE * 4);
            chunk_scan<CA, true><<<grid, BLOCK, CE * 4, stream>>>(
                charges, idx, dist, (float*)d_ws, npairs, natoms);
            chunk_reduce<CE, FB_NSL><<<(total / 4 + 255) / 256, 256, 0, stream>>>(
                (const float4*)d_ws, (float4*)out, total / 4);
        } else {
            hipMemsetAsync(d_out, 0, (size_t)total * sizeof(float), stream);
            hipFuncSetAttribute((const void*)chunk_scan<CA, false>,
                                hipFuncAttributeMaxDynamicSharedMemorySize, CE * 4);
            chunk_scan<CA, false><<<grid, BLOCK, CE * 4, stream>>>(
                charges, idx, dist, out, npairs, natoms);
        }
    } else {
        constexpr int CA2 = 2048, CE2 = CA2 * 4;
        const int C2 = (natoms + CA2 - 1) / CA2;
        const int grid2 = C2 * FB_NSL;
        const size_t ws_need = (size_t)grid2 * CE2 * sizeof(float);
        if (ws_size >= ws_need && (total & 3) == 0) {
            chunk_scan<CA2, true><<<grid2, BLOCK, CE2 * 4, stream>>>(
                charges, idx, dist, (float*)d_ws, npairs, natoms);
            chunk_reduce<CE2, FB_NSL><<<(total / 4 + 255) / 256, 256, 0, stream>>>(
                (const float4*)d_ws, (float4*)out, total / 4);
        } else {
            hipMemsetAsync(d_out, 0, (size_t)total * sizeof(float), stream);
            chunk_scan<CA2, false><<<grid2, BLOCK, CE2 * 4, stream>>>(
                charges, idx, dist, out, npairs, natoms);
        }
    }
}